// Round 9
// baseline (202.065 us; speedup 1.0000x reference)
//
#include <hip/hip_runtime.h>

// out[b,o] = x[b,:] @ W_lin[:,o] + x[b] @ W_nl[o] @ x[b]
// Symmetric GEMM form (K=640 via 10 folded 8x8 block-pairs of W_nl+W_nl^T).
// 2-WAY K-split on 32-row chunks: waves (2t,2t+1) co-own 16-row tile t;
// wave half w01 runs steps t=10*w01..10*w01+9 (bW[10][2] = 80 VGPRs).
// NEW this round: x rows come DIRECTLY from global into registers (8x
// global_load_dwordx4 per lane, 4-lane quad duplication absorbed by the
// VMEM coalescer + L2/L3 -- R4-verified access pattern), with a full
// iteration of register prefetch (Xp). This deletes the X-row ds_reads
// that R8's cycle budget showed were ~3100 cy/CU-iter of 2-way-conflicted
// LDS pipe occupancy, plus all staging. LDS now carries ONLY the partial
// reduce (R8-verified scheme, one barrier per chunk, double-buffered).
// Windows/scalars from register selects (R6-verified). Linear:
// bf16(0.5*W_lin), exact pow2, each w01 half adds once.

typedef __attribute__((ext_vector_type(8))) __bf16 bf16x8;
typedef __attribute__((ext_vector_type(4))) float floatx4;
typedef __attribute__((ext_vector_type(2))) float floatx2;

#define NB     524288
#define NCHUNK (NB / 32)    // 16384 chunks of 32 rows
#define GRID   512          // 2 blocks/CU, 32 iters/block, no tail
#define ITERS  (NCHUNK / GRID)
#define REDW   544          // 16 rows * 34 floats (pad 32->34)

__device__ __forceinline__ bf16x8 pack8(floatx4 a, floatx4 b) {
    bf16x8 f;
    #pragma unroll
    for (int j = 0; j < 4; ++j) { f[j] = (__bf16)a[j]; f[j + 4] = (__bf16)b[j]; }
    return f;
}

__global__ __launch_bounds__(256, 2)
void nnode_kernel(const float* __restrict__ x, const float* __restrict__ Wlin,
                  const float* __restrict__ Wnl, float* __restrict__ out) {
    __shared__ __align__(16) float red[2][2][2][REDW];    // 17 KiB [buf][tile][w01]

    const int tid  = threadIdx.x;
    const int wave = tid >> 6;
    const int lane = tid & 63;
    const int q    = lane >> 4;   // quad: A k-window / C row group
    const int col  = lane & 15;   // output column / A row
    const int tile = wave >> 1;   // 16-row tile (0,1) of the 32-row chunk
    const int w01  = wave & 1;    // K-split half

    // ---- B' fragments: this wave owns steps t = 10*w01 .. 10*w01+9 ----
    bf16x8 bW[10][2];
    #pragma unroll
    for (int kl = 0; kl < 10; ++kl) {
        const int t  = w01 * 10 + kl;
        const int p  = t >> 1, h = t & 1;
        const int pa = (p < 4) ? 0 : ((p < 7) ? 1 : ((p < 9) ? 2 : 3));
        const int pb = p - ((p < 4) ? 0 : ((p < 7) ? 3 : ((p < 9) ? 5 : 6)));
        const int i1 = 8 * pa + 4 * h + q;        // = 8a + u
        #pragma unroll
        for (int tt = 0; tt < 2; ++tt) {
            const float* base = Wnl + (size_t)(col + 16 * tt) * 1024;
            floatx4 v0 = *(const floatx4*)(base + i1 * 32 + 8 * pb);
            floatx4 v1 = *(const floatx4*)(base + i1 * 32 + 8 * pb + 4);
            if (pa != pb) {   // fold transposed block: += W_nl[o, 8b+v, 8a+u]
                #pragma unroll
                for (int j = 0; j < 4; ++j) {
                    v0[j] += base[(size_t)(8 * pb + j) * 32 + i1];
                    v1[j] += base[(size_t)(8 * pb + 4 + j) * 32 + i1];
                }
            }
            bW[kl][tt] = pack8(v0, v1);
        }
    }

    // ---- linear-part B fragments, half-scaled (both w01 halves add 1/2) ----
    bf16x8 bl0, bl1;
    #pragma unroll
    for (int j = 0; j < 8; ++j) {
        bl0[j] = (__bf16)(0.5f * Wlin[(q * 8 + j) * 32 + col]);
        bl1[j] = (__bf16)(0.5f * Wlin[(q * 8 + j) * 32 + col + 16]);
    }

    const bool q1 = (q & 1) != 0;
    const bool q2 = (q & 2) != 0;

    const int xrow = tile * 16 + col;     // this lane's x row within chunk
    // reduce map: thread -> (tile, row, col-quad)
    const int rT  = tid >> 7;
    const int rr  = (tid >> 3) & 15;
    const int rc4 = (tid & 7) * 4;

    // ---- prologue: load chunk blockIdx.x's row straight into registers ----
    floatx4 X[8];
    {
        const float* p0 = x + ((size_t)blockIdx.x * 32 + xrow) * 32;
        #pragma unroll
        for (int j = 0; j < 8; ++j)
            X[j] = *(const floatx4*)(p0 + 4 * j);
    }

    int chunk = blockIdx.x;
    for (int k = 0; k < ITERS; ++k, chunk += GRID) {
        const int cur = k & 1;

        // prefetch next chunk's row into registers (issued before compute;
        // an entire iteration of compute hides the HBM/L3 latency)
        floatx4 Xp[8];
        if (k < ITERS - 1) {
            const float* pn = x + ((size_t)(chunk + GRID) * 32 + xrow) * 32;
            #pragma unroll
            for (int j = 0; j < 8; ++j)
                Xp[j] = *(const floatx4*)(pn + 4 * j);
        }

        floatx4 acc0 = {0.f, 0.f, 0.f, 0.f};
        floatx4 acc1 = {0.f, 0.f, 0.f, 0.f};

        // scalar select X[i][q] via 3 cndmask (R6-verified)
        #define SELQ(V) (q2 ? (q1 ? (V)[3] : (V)[2]) : (q1 ? (V)[1] : (V)[0]))

        // linear part (half-scaled; window at q*8 via register selects)
        {
            floatx4 la0 = q2 ? (q1 ? X[6] : X[4]) : (q1 ? X[2] : X[0]);
            floatx4 la1 = q2 ? (q1 ? X[7] : X[5]) : (q1 ? X[3] : X[1]);
            bf16x8 af = pack8(la0, la1);
            acc0 = __builtin_amdgcn_mfma_f32_16x16x32_bf16(af, bl0, acc0, 0, 0, 0);
            acc1 = __builtin_amdgcn_mfma_f32_16x16x32_bf16(af, bl1, acc1, 0, 0, 0);
        }

        // one symmetric-packed k-step: af[j] = x[8a+4h+q] * x[8b+j]
        #define STEP(A, B, H, KL) {                                             \
            const float sc = SELQ(X[2 * (A) + (H)]);                            \
            floatx4 p0 = sc * X[2 * (B)];                                       \
            floatx4 p1 = sc * X[2 * (B) + 1];                                   \
            bf16x8 af = pack8(p0, p1);                                          \
            acc0 = __builtin_amdgcn_mfma_f32_16x16x32_bf16(af, bW[KL][0], acc0, 0, 0, 0); \
            acc1 = __builtin_amdgcn_mfma_f32_16x16x32_bf16(af, bW[KL][1], acc1, 0, 0, 0); }

        // wave-uniform branch; (a,b,h) literals match t = 10*w01 + kl
        if (w01 == 0) {
            STEP(0,0,0,0) STEP(0,0,1,1) STEP(0,1,0,2) STEP(0,1,1,3) STEP(0,2,0,4)
            STEP(0,2,1,5) STEP(0,3,0,6) STEP(0,3,1,7) STEP(1,1,0,8) STEP(1,1,1,9)
        } else {
            STEP(1,2,0,0) STEP(1,2,1,1) STEP(1,3,0,2) STEP(1,3,1,3) STEP(2,2,0,4)
            STEP(2,2,1,5) STEP(2,3,0,6) STEP(2,3,1,7) STEP(3,3,0,8) STEP(3,3,1,9)
        }
        #undef STEP
        #undef SELQ

        // ---- partials to LDS (R8 scheme: row = q*4+r2, col = col(+16)) ----
        {
            float* rp = &red[cur][tile][w01][0];
            #pragma unroll
            for (int r2 = 0; r2 < 4; ++r2) {
                rp[(q * 4 + r2) * 34 + col]      = acc0[r2];
                rp[(q * 4 + r2) * 34 + col + 16] = acc1[r2];
            }
        }
        __syncthreads();

        // ---- reduce 2 partials; thread owns (tile rT, row rr, cols rc4..rc4+3) ----
        {
            const float* b0p = &red[cur][rT][0][rr * 34 + rc4];
            const float* b1p = &red[cur][rT][1][rr * 34 + rc4];
            floatx2 u0 = *(const floatx2*)(b0p);
            floatx2 u1 = *(const floatx2*)(b0p + 2);
            floatx2 v0 = *(const floatx2*)(b1p);
            floatx2 v1 = *(const floatx2*)(b1p + 2);
            floatx4 s = {u0.x + v0.x, u0.y + v0.y, u1.x + v1.x, u1.y + v1.y};
            *(floatx4*)(out + ((size_t)chunk * 32 + rT * 16 + rr) * 32 + rc4) = s;
        }

        // roll the prefetched row into X for the next iteration
        if (k < ITERS - 1) {
            #pragma unroll
            for (int j = 0; j < 8; ++j) X[j] = Xp[j];
        }
        // double-buffered red; the single barrier orders reuse
    }
}

extern "C" void kernel_launch(void* const* d_in, const int* in_sizes, int n_in,
                              void* d_out, int out_size, void* d_ws, size_t ws_size,
                              hipStream_t stream) {
    const float* x    = (const float*)d_in[0];
    const float* Wlin = (const float*)d_in[1];
    const float* Wnl  = (const float*)d_in[2];
    float* out        = (float*)d_out;
    nnode_kernel<<<dim3(GRID), dim3(256), 0, stream>>>(x, Wlin, Wnl, out);
}

// Round 10
// 170.705 us; speedup vs baseline: 1.1837x; 1.1837x over previous
//
#include <hip/hip_runtime.h>

// out[b,o] = x[b,:] @ W_lin[:,o] + x[b] @ W_nl[o] @ x[b]
// Symmetric GEMM form (K=640 via 10 folded 8x8 block-pairs of W_nl+W_nl^T).
// QUARTER-SPLIT: the 4 waves of a block map to (K-half w01) x (col-half):
// wave runs steps t=10*w01..10*w01+9 for ONE 16-col half -> bW[10] = 40
// VGPRs (half of R8's 80), acc = 4. Per-wave ~115 regs => (256,3) = 3
// blocks/CU = 12 waves/CU (+50% vs R8's 8) with zero spill margin issues.
// Chunk = 16 rows (R6-verified staging + XW swizzle + 8x b128 full-row
// register reads + register-select windows/scalars). Partial exchange
// halves: 2 buffers (per w01; col-halves share one buffer at disjoint
// columns), R6-verified reduce over 2 partials. Linear: bf16(0.5*W_lin)
// per w01 half (exact pow2). One barrier per chunk, double-buffered.

typedef __attribute__((ext_vector_type(8))) __bf16 bf16x8;
typedef __attribute__((ext_vector_type(4))) float floatx4;
typedef __attribute__((ext_vector_type(2))) float floatx2;

#define NB     524288
#define NCHUNK (NB / 16)    // 32768 chunks of 16 rows
#define GRID   768          // 3 blocks/CU; tail: 512 blocks run 43, rest 42
#define REDW   544          // 16 rows * 34 floats (pad 32->34)

// xor-swizzled x word (R3/R6-verified): row r (0..15), element e (0..31)
__device__ __forceinline__ int XW(int r, int e) {
    return r * 32 + ((((e >> 2) ^ (r & 7)) << 2) | (e & 3));
}

__device__ __forceinline__ bf16x8 pack8(floatx4 a, floatx4 b) {
    bf16x8 f;
    #pragma unroll
    for (int j = 0; j < 4; ++j) { f[j] = (__bf16)a[j]; f[j + 4] = (__bf16)b[j]; }
    return f;
}

__global__ __launch_bounds__(256, 3)
void nnode_kernel(const float* __restrict__ x, const float* __restrict__ Wlin,
                  const float* __restrict__ Wnl, float* __restrict__ out) {
    __shared__ __align__(16) float xs[2][512];          // 4 KiB, swizzled 16x32
    __shared__ __align__(16) float red[2][2][REDW];     // 8.7 KiB [buf][w01]

    const int tid  = threadIdx.x;
    const int wave = tid >> 6;
    const int lane = tid & 63;
    const int q    = lane >> 4;   // quad: A k-window / C row group
    const int col  = lane & 15;   // output column (within half) / A row
    const int half = wave & 1;    // col half 0/1
    const int w01  = wave >> 1;   // K-split half 0/1

    // ---- B' fragments: steps t = 10*w01 .. 10*w01+9, OWN col half only ----
    bf16x8 bW[10];
    #pragma unroll
    for (int kl = 0; kl < 10; ++kl) {
        const int t  = w01 * 10 + kl;
        const int p  = t >> 1, h = t & 1;
        const int pa = (p < 4) ? 0 : ((p < 7) ? 1 : ((p < 9) ? 2 : 3));
        const int pb = p - ((p < 4) ? 0 : ((p < 7) ? 3 : ((p < 9) ? 5 : 6)));
        const int i1 = 8 * pa + 4 * h + q;        // = 8a + u
        const float* base = Wnl + (size_t)(col + 16 * half) * 1024;
        floatx4 v0 = *(const floatx4*)(base + i1 * 32 + 8 * pb);
        floatx4 v1 = *(const floatx4*)(base + i1 * 32 + 8 * pb + 4);
        if (pa != pb) {   // fold transposed block: += W_nl[o, 8b+v, 8a+u]
            #pragma unroll
            for (int j = 0; j < 4; ++j) {
                v0[j] += base[(size_t)(8 * pb + j) * 32 + i1];
                v1[j] += base[(size_t)(8 * pb + 4 + j) * 32 + i1];
            }
        }
        bW[kl] = pack8(v0, v1);
    }

    // ---- linear-part B fragment, half-scaled (both w01 halves add 1/2) ----
    bf16x8 bl;
    #pragma unroll
    for (int j = 0; j < 8; ++j)
        bl[j] = (__bf16)(0.5f * Wlin[(q * 8 + j) * 32 + 16 * half + col]);

    const bool q1 = (q & 1) != 0;
    const bool q2 = (q & 2) != 0;

    const int srow  = tid >> 4;          // staging/reduce row 0..15
    const int scol2 = (tid & 15) * 2;    // staging/reduce elem pair

    const int n = 42 + ((blockIdx.x < (NCHUNK - 42 * GRID)) ? 1 : 0);

    // ---- prologue: stage chunk blockIdx.x into xs[0] (R6 verbatim) ----
    {
        floatx2 v = *(const floatx2*)(x + (size_t)blockIdx.x * 512 + tid * 2);
        *(floatx2*)&xs[0][XW(srow, scol2)] = v;
    }
    __syncthreads();

    int chunk = blockIdx.x;
    for (int k = 0; k < n; ++k, chunk += GRID) {
        const int cur = k & 1;

        // prefetch next chunk (coalesced 2KB/block); landed after compute
        floatx2 pre;
        if (k < n - 1)
            pre = *(const floatx2*)(x + (size_t)(chunk + GRID) * 512 + tid * 2);

        // full row -> registers: 8x b128 (quad broadcast + 2-way banked)
        const float* xb = xs[cur];
        floatx4 X[8];
        #pragma unroll
        for (int j = 0; j < 8; ++j)
            X[j] = *(const floatx4*)&xb[XW(col, 4 * j)];

        floatx4 acc = {0.f, 0.f, 0.f, 0.f};

        // scalar select X[i][q] via 3 cndmask (R6-verified)
        #define SELQ(V) (q2 ? (q1 ? (V)[3] : (V)[2]) : (q1 ? (V)[1] : (V)[0]))

        // linear part (half-scaled; window at q*8 via register selects)
        {
            floatx4 la0 = q2 ? (q1 ? X[6] : X[4]) : (q1 ? X[2] : X[0]);
            floatx4 la1 = q2 ? (q1 ? X[7] : X[5]) : (q1 ? X[3] : X[1]);
            bf16x8 af = pack8(la0, la1);
            acc = __builtin_amdgcn_mfma_f32_16x16x32_bf16(af, bl, acc, 0, 0, 0);
        }

        // one symmetric-packed k-step: af[j] = x[8a+4h+q] * x[8b+j]
        #define STEP(A, B, H, KL) {                                             \
            const float sc = SELQ(X[2 * (A) + (H)]);                            \
            floatx4 p0 = sc * X[2 * (B)];                                       \
            floatx4 p1 = sc * X[2 * (B) + 1];                                   \
            bf16x8 af = pack8(p0, p1);                                          \
            acc = __builtin_amdgcn_mfma_f32_16x16x32_bf16(af, bW[KL], acc, 0, 0, 0); }

        // wave-uniform branch; (a,b,h) literals match t = 10*w01 + kl
        if (w01 == 0) {
            STEP(0,0,0,0) STEP(0,0,1,1) STEP(0,1,0,2) STEP(0,1,1,3) STEP(0,2,0,4)
            STEP(0,2,1,5) STEP(0,3,0,6) STEP(0,3,1,7) STEP(1,1,0,8) STEP(1,1,1,9)
        } else {
            STEP(1,2,0,0) STEP(1,2,1,1) STEP(1,3,0,2) STEP(1,3,1,3) STEP(2,2,0,4)
            STEP(2,2,1,5) STEP(2,3,0,6) STEP(2,3,1,7) STEP(3,3,0,8) STEP(3,3,1,9)
        }
        #undef STEP
        #undef SELQ

        // ---- partials: col-halves share red[cur][w01] at disjoint cols ----
        {
            float* rp = &red[cur][w01][0];
            #pragma unroll
            for (int r2 = 0; r2 < 4; ++r2)
                rp[(q * 4 + r2) * 34 + 16 * half + col] = acc[r2];
        }
        // land the prefetched chunk into the other x buffer
        if (k < n - 1)
            *(floatx2*)&xs[cur ^ 1][XW(srow, scol2)] = pre;
        __syncthreads();

        // ---- reduce 2 partials; thread owns elems [2*tid, 2*tid+1] ----
        {
            const float* rb0 = &red[cur][0][srow * 34 + scol2];
            const float* rb1 = &red[cur][1][srow * 34 + scol2];
            floatx2 a = *(const floatx2*)rb0;
            floatx2 b = *(const floatx2*)rb1;
            floatx2 s = {a.x + b.x, a.y + b.y};
            *(floatx2*)(out + (size_t)chunk * 512 + tid * 2) = s;
        }
        // double-buffered xs/red; the single barrier orders reuse
    }
}

extern "C" void kernel_launch(void* const* d_in, const int* in_sizes, int n_in,
                              void* d_out, int out_size, void* d_ws, size_t ws_size,
                              hipStream_t stream) {
    const float* x    = (const float*)d_in[0];
    const float* Wlin = (const float*)d_in[1];
    const float* Wnl  = (const float*)d_in[2];
    float* out        = (float*)d_out;
    nnode_kernel<<<dim3(GRID), dim3(256), 0, stream>>>(x, Wlin, Wnl, out);
}